// Round 3
// baseline (346.814 us; speedup 1.0000x reference)
//
#include <hip/hip_runtime.h>
#include <hip/hip_bf16.h>

#define N_ATOMS 32768
#define N_EDGESC 262144
#define ATOM_F 256
#define EDGE_F 128
#define OUT_F 512
#define N_GAUSS 50
#define IN_F 690
#define NCHUNK 11

#define BM 64
#define BN 256
#define NTHREADS 256

using f32x4  = __attribute__((ext_vector_type(4))) float;
using short8 = __attribute__((ext_vector_type(8))) short;

__device__ __forceinline__ unsigned short f2bf(float f) {
  unsigned int u = __builtin_bit_cast(unsigned int, f);
  u += 0x7fffu + ((u >> 16) & 1u);   // round-to-nearest-even
  return (unsigned short)(u >> 16);
}

// ---- detect int64 vs int32 edge_index (deterministic, data-driven) ----
__global__ void detect_idx_kernel(const unsigned int* __restrict__ ei, int* __restrict__ flag) {
  if (threadIdx.x == 0) {
    int ok = 1;
    for (int i = 0; i < 64; ++i) {
      unsigned int lo = ei[2 * i], hi = ei[2 * i + 1];
      if (hi != 0u || lo >= (unsigned)N_ATOMS) { ok = 0; break; }
    }
    *flag = ok;  // 1 => int64 layout
  }
}

// ---- W (512x690 fp32 [n][k]) -> Wp bf16 in MFMA-fragment order ----
// Fragment (kc, ks, nt): 64 lanes x 16B contiguous (1 KB).
// lane l holds B[n = nt*16 + (l&15)][k = kc*64 + ks*32 + (l>>4)*8 + j], j=0..7
__global__ void prep_w_kernel(const float* __restrict__ W, unsigned short* __restrict__ Wp) {
  int g = blockIdx.x * blockDim.x + threadIdx.x;   // one thread per fragment-lane
  if (g >= NCHUNK * 2 * 32 * 64) return;
  int l  = g & 63;
  int nt = (g >> 6) & 31;
  int ks = (g >> 11) & 1;
  int kc = g >> 12;
  int n  = nt * 16 + (l & 15);
  int k0 = kc * 64 + ks * 32 + ((l >> 4) << 3);
  unsigned int u[4];
#pragma unroll
  for (int p = 0; p < 4; ++p) {
    int ka = k0 + 2 * p, kb = k0 + 2 * p + 1;
    float va = (ka < IN_F) ? W[n * IN_F + ka] : 0.0f;
    float vb = (kb < IN_F) ? W[n * IN_F + kb] : 0.0f;
    u[p] = (unsigned)f2bf(va) | ((unsigned)f2bf(vb) << 16);
  }
  *(uint4*)(Wp + (size_t)g * 8) = make_uint4(u[0], u[1], u[2], u[3]);
}

// ---- fused gather + gaussian + GEMM ----
// BM=64 edges x BN=256 cols per block; 4 waves, wave tile 64x64; 3 blocks/CU.
__global__ __launch_bounds__(NTHREADS, 3) void gemm_kernel(
    const float* __restrict__ h, const float* __restrict__ m,
    const float* __restrict__ magft, const void* __restrict__ ei,
    const int* __restrict__ flagp, const unsigned short* __restrict__ Wp,
    float* __restrict__ out)
{
  __shared__ __align__(16) unsigned short As[2][BM * 64];  // 2 x 8 KB, XOR-swizzled
  __shared__ int sIdx[BM], tIdx[BM];
  __shared__ float dLDS[BM];

  const int tid = threadIdx.x;
  const int eb  = blockIdx.y * BM;
  const int ntb = blockIdx.x * 16;     // base n-tile (16 cols each)

  const int use64 = *flagp;
  if (tid < BM) {
    int e = eb + tid;
    int s, tg;
    if (use64) {
      const long long* p = (const long long*)ei;
      s  = (int)p[e];
      tg = (int)p[N_EDGESC + e];
    } else {
      const int* p = (const int*)ei;
      s  = p[e];
      tg = p[N_EDGESC + e];
    }
    sIdx[tid] = s;
    tIdx[tid] = tg;
    float ax = magft[3 * s],  ay = magft[3 * s + 1],  az = magft[3 * s + 2];
    float bx = magft[3 * tg], by = magft[3 * tg + 1], bz = magft[3 * tg + 2];
    dLDS[tid] = ax * bx + ay * by + az * bz;
  }
  __syncthreads();

  const int lane = tid & 63;
  const int wc   = tid >> 6;     // wave 0..3 -> N quarter (64 cols)

  const int ar = tid >> 2;       // staging row 0..63
  const int aq = tid & 3;        // staging quarter (16 fp32 cols)

  float4 v[4];                   // staged chunk (16 fp32 per thread)

  // ---- phase 1: issue loads (or compute gaussians) into regs ----
  auto stage_load = [&](int kchunk) {
    if (kchunk < 10) {
      const float* p;
      if (kchunk < 8) {
        int atom = (kchunk < 4) ? sIdx[ar] : tIdx[ar];
        p = h + (size_t)atom * ATOM_F + (kchunk & 3) * 64 + aq * 16;
      } else {
        p = m + (size_t)(eb + ar) * EDGE_F + (kchunk & 1) * 64 + aq * 16;
      }
#pragma unroll
      for (int j = 0; j < 4; ++j) v[j] = ((const float4*)p)[j];
    } else {
      float d = dLDS[ar];
      const float step  = 3.0f / 49.0f;
      const float coeff = -0.5f / (step * step);
#pragma unroll
      for (int j = 0; j < 4; ++j) {
#pragma unroll
        for (int t = 0; t < 4; ++t) {
          int c = aq * 16 + j * 4 + t;
          float o = -1.5f + step * (float)c;
          v[j][t] = (c < N_GAUSS) ? __expf(coeff * (d - o) * (d - o)) : 0.0f;
        }
      }
    }
  };

  // ---- phase 3: cvt + swizzled ds_write ----
  auto stage_write = [&](int buf) {
    unsigned int u[8];
#pragma unroll
    for (int j = 0; j < 4; ++j) {
      u[2 * j]     = (unsigned)f2bf(v[j].x) | ((unsigned)f2bf(v[j].y) << 16);
      u[2 * j + 1] = (unsigned)f2bf(v[j].z) | ((unsigned)f2bf(v[j].w) << 16);
    }
    char* base = (char*)&As[buf][0] + ar * 128;
    const int sw = (ar & 7) << 4;
    *(uint4*)(base + ((aq * 32)      ^ sw)) = make_uint4(u[0], u[1], u[2], u[3]);
    *(uint4*)(base + ((aq * 32 + 16) ^ sw)) = make_uint4(u[4], u[5], u[6], u[7]);
  };

  f32x4 acc[4][4];
#pragma unroll
  for (int i = 0; i < 4; ++i)
#pragma unroll
    for (int j = 0; j < 4; ++j) acc[i][j] = (f32x4){0.f, 0.f, 0.f, 0.f};

  stage_load(0);
  stage_write(0);
  __syncthreads();

  const short8* Wp8 = (const short8*)Wp;

  for (int kc = 0; kc < NCHUNK; ++kc) {
    const int cur = kc & 1;
    if (kc < NCHUNK - 1) stage_load(kc + 1);   // issue gathers early

    const char* abase = (const char*)&As[cur][0];
#pragma unroll
    for (int ks = 0; ks < 2; ++ks) {
      short8 b[4];
#pragma unroll
      for (int ni = 0; ni < 4; ++ni)
        b[ni] = Wp8[(size_t)(((kc * 2 + ks) * 32 + ntb + wc * 4 + ni) << 6) + lane];
      short8 a[4];
#pragma unroll
      for (int mi = 0; mi < 4; ++mi) {
        int row = mi * 16 + (lane & 15);
        int colb = (ks * 64 + ((lane >> 4) << 4)) ^ ((row & 7) << 4);
        a[mi] = *(const short8*)(abase + row * 128 + colb);
      }
#pragma unroll
      for (int mi = 0; mi < 4; ++mi)
#pragma unroll
        for (int ni = 0; ni < 4; ++ni)
          acc[mi][ni] = __builtin_amdgcn_mfma_f32_16x16x32_bf16(a[mi], b[ni], acc[mi][ni], 0, 0, 0);
    }

    if (kc < NCHUNK - 1) {
      stage_write(cur ^ 1);                    // cvt + ds_write after compute
      __syncthreads();
    }
  }

  // ---- epilogue: C/D layout col=lane&15, row=(lane>>4)*4+j ----
#pragma unroll
  for (int mi = 0; mi < 4; ++mi) {
    int row0 = eb + mi * 16 + ((lane >> 4) << 2);
#pragma unroll
    for (int ni = 0; ni < 4; ++ni) {
      int col = ntb * 16 + wc * 64 + ni * 16 + (lane & 15);
#pragma unroll
      for (int j = 0; j < 4; ++j) {
        out[(size_t)(row0 + j) * OUT_F + col] = acc[mi][ni][j];
      }
    }
  }
}

extern "C" void kernel_launch(void* const* d_in, const int* in_sizes, int n_in,
                              void* d_out, int out_size, void* d_ws, size_t ws_size,
                              hipStream_t stream) {
  const float* h     = (const float*)d_in[0];
  const float* m     = (const float*)d_in[1];
  const float* magft = (const float*)d_in[2];
  const void*  ei    = d_in[3];
  const float* W     = (const float*)d_in[4];
  float* out = (float*)d_out;

  char* ws = (char*)d_ws;
  int* flag = (int*)ws;
  unsigned short* Wp = (unsigned short*)(ws + 256);  // 704 KB fragment-packed W

  detect_idx_kernel<<<1, 64, 0, stream>>>((const unsigned int*)ei, flag);
  prep_w_kernel<<<(NCHUNK * 2 * 32 * 64 + 255) / 256, 256, 0, stream>>>(W, Wp);

  gemm_kernel<<<dim3(OUT_F / BN, N_EDGESC / BM), NTHREADS, 0, stream>>>(h, m, magft, ei, flag, Wp, out);
}